// Round 11
// baseline (569.358 us; speedup 1.0000x reference)
//
#include <hip/hip_runtime.h>
#include <cstddef>

#define NB 256   // batch
#define NT 512   // time
#define ND 128   // input dim
#define NH 128   // hidden
#define NG 512   // 4*H
#define NM (NB * NT)     // total input-GEMM rows
#define NMP (NM + 64)    // legacy sizing constant for ws layout (G fits under NG*NMP)
#define LBLK 16          // batch rows per k_lstm block
#define TSTR ((size_t)16 * 512 * 16)   // G elems per timestep (16 chunks x 512 j x 16 b)

constexpr float F_EPS  = 1e-7f;
constexpr float F_TEMP = 0.1f;

typedef _Float16 h4_t __attribute__((ext_vector_type(4)));
typedef _Float16 h8_t __attribute__((ext_vector_type(8)));
typedef float    fx4  __attribute__((ext_vector_type(4)));

__device__ __forceinline__ float fexp2(float x) {
#if defined(__has_builtin)
#  if __has_builtin(__builtin_amdgcn_exp2f)
    return __builtin_amdgcn_exp2f(x);
#  else
    return exp2f(x);
#  endif
#else
    return exp2f(x);
#endif
}
__device__ __forceinline__ float frcp(float x) {
#if defined(__has_builtin)
#  if __has_builtin(__builtin_amdgcn_rcpf)
    return __builtin_amdgcn_rcpf(x);
#  else
    return 1.0f / x;
#  endif
#else
    return 1.0f / x;
#endif
}
__device__ __forceinline__ float sig(float x) { return 1.0f / (1.0f + expf(-x)); }

// LDS-ordering-only barrier: does NOT drain vmcnt (global loads/stores stay in
// flight). lgkmcnt(0) orders our ds ops before the barrier; sched_barrier pins
// it (rule #18).
__device__ __forceinline__ void bar_lds() {
    asm volatile("s_waitcnt lgkmcnt(0)" ::: "memory");
    __builtin_amdgcn_sched_barrier(0);
    __builtin_amdgcn_s_barrier();
}

// ---------------- kernel 1: weight f16 conversion + w^2 sums + concrete masks -------
__global__ __launch_bounds__(256) void k_convert(const float* __restrict__ wih,
        const float* __restrict__ whh, const float* __restrict__ pl,
        const float* __restrict__ plr, const float* __restrict__ unif_x,
        const float* __restrict__ unif_h, _Float16* __restrict__ wih_h,
        _Float16* __restrict__ whh_h, _Float16* __restrict__ mask_x,
        _Float16* __restrict__ mask_h, float* __restrict__ partial) {
    int i = blockIdx.x * 256 + threadIdx.x;    // float4 index, 16384 total
    float4 a = ((const float4*)wih)[i];
    float4 b = ((const float4*)whh)[i];
    h4_t ah, bh;
    ah[0] = (_Float16)a.x; ah[1] = (_Float16)a.y; ah[2] = (_Float16)a.z; ah[3] = (_Float16)a.w;
    bh[0] = (_Float16)b.x; bh[1] = (_Float16)b.y; bh[2] = (_Float16)b.z; bh[3] = (_Float16)b.w;
    *(h4_t*)(wih_h + 4 * (size_t)i) = ah;
    *(h4_t*)(whh_h + 4 * (size_t)i) = bh;
    float sk = a.x * a.x + a.y * a.y + a.z * a.z + a.w * a.w;
    float sr = b.x * b.x + b.y * b.y + b.z * b.z + b.w * b.w;
    for (int off = 32; off; off >>= 1) {
        sk += __shfl_down(sk, off);
        sr += __shfl_down(sr, off);
    }
    if ((threadIdx.x & 63) == 0) {
        atomicAdd(partial + 0, sk);
        atomicAdd(partial + 1, sr);
    }
    // concrete-dropout masks: threads 0..8191 -> mask_x, 8192..16383 -> mask_h
    float p;
    const float* up;
    _Float16* mp;
    int mi;
    if (i < 8192) { p = sig(pl[0]);  up = unif_x; mp = mask_x; mi = i; }
    else          { p = sig(plr[0]); up = unif_h; mp = mask_h; mi = i - 8192; }
    float4 u = ((const float4*)up)[mi];
    float base = logf(p + F_EPS) - logf(1.f - p + F_EPS);
    float inv  = 1.f / (1.f - p);
    h4_t m4;
    {
        float uu[4] = {u.x, u.y, u.z, u.w};
#pragma unroll
        for (int e = 0; e < 4; ++e) {
            float lg = base + logf(uu[e] + F_EPS) - logf(1.f - uu[e] + F_EPS);
            float mk = 1.f - sig(lg / F_TEMP);
            m4[e] = (_Float16)(mk * inv);
        }
    }
    *(h4_t*)(mp + 4 * (size_t)mi) = m4;
}

// ---------------- kernel 1b: finalize scalar regularization outputs ----------------
__global__ void k_tail(const float* __restrict__ bih, const float* __restrict__ bhh,
                       const float* __restrict__ pl, const float* __restrict__ plr,
                       const float* __restrict__ partial, float* __restrict__ out_tail) {
    __shared__ float red[8];
    int t = threadIdx.x;  // 512 threads
    float v = bih[t], w2 = bhh[t];
    float sb = v * v + w2 * w2;
    for (int off = 32; off; off >>= 1) sb += __shfl_down(sb, off);
    int wid = t >> 6, lane = t & 63;
    if (lane == 0) red[wid] = sb;
    __syncthreads();
    if (t == 0) {
        float SB = 0.f;
        for (int i = 0; i < 8; i++) SB += red[i];
        float SK = partial[0], SR = partial[1];
        float p  = sig(pl[0]);
        float pr = sig(plr[0]);
        float wr = 1e-6f * (SK / (1.f - p) + SR / (1.f - pr));
        float br = 1e-6f * SB;
        float ek = p * logf(p) + (1.f - p) * logf(1.f - p);
        float er = pr * logf(pr) + (1.f - pr) * logf(1.f - pr);
        float dr = 1e-5f * ((float)ND * ek + (float)NH * er);
        out_tail[0] = wr + br + dr;
        out_tail[1] = p;
        out_tail[2] = pr;
    }
}

// ---------------- kernel 2: f16 MFMA input GEMM (unchanged from r10) ----------------
// G layout: G[((t*16 + (b>>4))*512 + j)*16 + (b&15)] — per-(t,bchunk) slab is
// 16KB contiguous.
__global__ __launch_bounds__(256, 2) void k_gemm(const float* __restrict__ x,
        const _Float16* __restrict__ wih_h, const float* __restrict__ bih,
        const float* __restrict__ bhh, const _Float16* __restrict__ mask_x,
        _Float16* __restrict__ Gp) {
    __shared__ _Float16 Alds[128 * 128];
    __shared__ _Float16 Wlds[128 * 128];
    __shared__ float bsum[128];
    int t  = threadIdx.x;
    int j0 = blockIdx.y * 128;           // gate-col block
    int tg  = blockIdx.x >> 1;           // timestep of this tile
    int b0g = (blockIdx.x & 1) * 128;    // batch base of this tile

    if (t < 128) bsum[t] = bih[j0 + t] + bhh[j0 + t];
    __syncthreads();

#pragma unroll
    for (int i = 0; i < 8; i++) {
        int s   = i * 256 + t;
        int row = s >> 4;                 // 0..127 (batch-local)
        int s16 = s & 15;                 // 16B slot within row
        int bb  = b0g + row;
        const float4* xp = (const float4*)(x + ((size_t)bb * NT + tg) * ND + s16 * 8);
        float4 v0 = xp[0], v1 = xp[1];
        h8_t mk = *(const h8_t*)(mask_x + (size_t)bb * ND + s16 * 8);
        h8_t hv;
        hv[0] = (_Float16)(v0.x * (float)mk[0]); hv[1] = (_Float16)(v0.y * (float)mk[1]);
        hv[2] = (_Float16)(v0.z * (float)mk[2]); hv[3] = (_Float16)(v0.w * (float)mk[3]);
        hv[4] = (_Float16)(v1.x * (float)mk[4]); hv[5] = (_Float16)(v1.y * (float)mk[5]);
        hv[6] = (_Float16)(v1.z * (float)mk[6]); hv[7] = (_Float16)(v1.w * (float)mk[7]);
        *(h8_t*)(&Alds[(size_t)row * 128 + ((s16 ^ (row & 7)) << 3)]) = hv;
        h8_t wv = *(const h8_t*)(wih_h + (size_t)(j0 + row) * ND + s16 * 8);
        *(h8_t*)(&Wlds[(size_t)row * 128 + ((s16 ^ (row & 7)) << 3)]) = wv;
    }
    __syncthreads();

    int w  = t >> 6, l = t & 63;
    int lr = l & 15, lg = l >> 4;
    fx4 acc[2][8] = {};
#pragma unroll
    for (int kk = 0; kk < 4; kk++) {
        h8_t af[2], bf[8];
#pragma unroll
        for (int mt = 0; mt < 2; mt++) {
            int r = 32 * w + 16 * mt + lr;
            af[mt] = *(const h8_t*)(&Alds[(size_t)r * 128 + (((4 * kk + lg) ^ (r & 7)) << 3)]);
        }
#pragma unroll
        for (int nt = 0; nt < 8; nt++) {
            int r = 16 * nt + lr;
            bf[nt] = *(const h8_t*)(&Wlds[(size_t)r * 128 + (((4 * kk + lg) ^ (r & 7)) << 3)]);
        }
#pragma unroll
        for (int mt = 0; mt < 2; mt++)
#pragma unroll
            for (int nt = 0; nt < 8; nt++)
                acc[mt][nt] = __builtin_amdgcn_mfma_f32_16x16x32_f16(af[mt], bf[nt], acc[mt][nt], 0, 0, 0);
    }

#pragma unroll
    for (int mt = 0; mt < 2; mt++)
#pragma unroll
        for (int nt = 0; nt < 8; nt++) {
            int j  = j0 + 16 * nt + lr;
            int bb = b0g + 32 * w + 16 * mt + 4 * lg;   // batch (4 consecutive via h4)
            float bv = bsum[16 * nt + lr];
            h4_t o;
#pragma unroll
            for (int q = 0; q < 4; q++) o[q] = (_Float16)(acc[mt][nt][q] + bv);
            size_t addr = (((size_t)tg * 16 + (bb >> 4)) * 512 + j) * 16 + (bb & 15);
            *(h4_t*)(Gp + addr) = o;
        }
}

// ---------------- kernel 3: MFMA recurrence — prefetch-4, split chains, phased act --
// 16 blocks x 16 batch rows, 512 threads (8 waves). Wave wv owns hidden units
// [16wv,16wv+16); 4 n-tiles = 4 GATES -> i,f,g,o of (batch m, unit u) IN-LANE.
// W_hh pinned B-fragments (64 VGPR). r10 diagnosis: active-CU VALUBusy ~68%,
// ~700cyc residual stalls. Fixes: (a) prefetch depth 4 (~3.5 steps > HBM lat),
// (b) MFMA acc split into 2x2-deep chains (-~100cyc latency), (c) activation
// phased (all s -> all exp -> all rcp -> state chains) to pipeline the trans
// unit instead of 4 serial per-state chains.
__global__ __launch_bounds__(512, 1)
void k_lstm(const _Float16* __restrict__ Gp, const _Float16* __restrict__ whh_h,
            const _Float16* __restrict__ maskh,
            float* __restrict__ xout, float* __restrict__ hlast) {
    __shared__ _Float16 hd[2][LBLK * 128];
    int tid = threadIdx.x;
    int l   = tid & 63;
    int wv  = tid >> 6;            // 0..7
    int lr  = l & 15;              // A-row (batch) for reads / C-col (unit)
    int lq  = l >> 4;              // quarter
    int bc  = blockIdx.x;          // batch chunk 0..15
    int b0  = bc * LBLK;
    int u   = wv * 16 + lr;        // hidden unit owned

    // B-fragments: bf[g][kk] = W_hh[g*128+u][kk*32 + lq*8 .. +8)
    h8_t bf[4][4];
#pragma unroll
    for (int g = 0; g < 4; ++g)
#pragma unroll
        for (int kk = 0; kk < 4; ++kk)
            bf[g][kk] = *(const h8_t*)(whh_h + (size_t)(g * 128 + u) * NH + kk * 32 + lq * 8);

    float msk[4], c4[4], hl[4];
#pragma unroll
    for (int r = 0; r < 4; ++r) {
        msk[r] = (float)maskh[(size_t)(b0 + lq * 4 + r) * NH + u];
        c4[r] = 0.f; hl[r] = 0.f;
    }

    // G stream bases (t=0): slab-contiguous layout
    const _Float16* gp0 = Gp + ((size_t)bc * 512 + 0 * 128 + u) * 16 + lq * 4;
    const _Float16* gp1 = Gp + ((size_t)bc * 512 + 1 * 128 + u) * 16 + lq * 4;
    const _Float16* gp2 = Gp + ((size_t)bc * 512 + 2 * 128 + u) * 16 + lq * 4;
    const _Float16* gp3 = Gp + ((size_t)bc * 512 + 3 * 128 + u) * 16 + lq * 4;
    float* xo0 = xout + (size_t)(b0 + lq * 4 + 0) * NT * NH + u;
    float* xo1 = xout + (size_t)(b0 + lq * 4 + 1) * NT * NH + u;
    float* xo2 = xout + (size_t)(b0 + lq * 4 + 2) * NT * NH + u;
    float* xo3 = xout + (size_t)(b0 + lq * 4 + 3) * NT * NH + u;

    // zero-init hd parity 0 (h0 state)
    {
        char* h0 = (char*)&hd[0][0];
#pragma unroll
        for (int r = 0; r < 4; ++r) {
            int m = lq * 4 + r;
            *(_Float16*)(h0 + m * 256 + ((2 * u) ^ ((m & 7) << 4))) = (_Float16)0.f;
        }
    }

    // preload t=0..3 (sets A,B,C,D)
    h4_t A0 = *(const h4_t*)(gp0 + 0 * TSTR), A1 = *(const h4_t*)(gp1 + 0 * TSTR);
    h4_t A2 = *(const h4_t*)(gp2 + 0 * TSTR), A3 = *(const h4_t*)(gp3 + 0 * TSTR);
    h4_t B0 = *(const h4_t*)(gp0 + 1 * TSTR), B1 = *(const h4_t*)(gp1 + 1 * TSTR);
    h4_t B2 = *(const h4_t*)(gp2 + 1 * TSTR), B3 = *(const h4_t*)(gp3 + 1 * TSTR);
    h4_t C0 = *(const h4_t*)(gp0 + 2 * TSTR), C1 = *(const h4_t*)(gp1 + 2 * TSTR);
    h4_t C2 = *(const h4_t*)(gp2 + 2 * TSTR), C3 = *(const h4_t*)(gp3 + 2 * TSTR);
    h4_t D0 = *(const h4_t*)(gp0 + 3 * TSTR), D1 = *(const h4_t*)(gp1 + 3 * TSTR);
    h4_t D2 = *(const h4_t*)(gp2 + 3 * TSTR), D3 = *(const h4_t*)(gp3 + 3 * TSTR);
    __syncthreads();   // hd[0] init visible

    constexpr float KS = -1.44269504088896f;   // sigmoid exp2 scale
    constexpr float KT =  2.885390081777927f;  // tanh exp2 scale

    auto STEPF = [&](h4_t& GA0, h4_t& GA1, h4_t& GA2, h4_t& GA3,
                     int TT, int par) {
        // pin B-frags (prevent remat/spill of W_hh)
#pragma unroll
        for (int g = 0; g < 4; ++g)
#pragma unroll
            for (int kk = 0; kk < 4; ++kk) asm volatile("" : "+v"(bf[g][kk]));
        const char* hb = (const char*)&hd[par][0];
        // split accumulation: two 2-deep chains per gate
        fx4 lo0 = {0.f,0.f,0.f,0.f}, lo1 = lo0, lo2 = lo0, lo3 = lo0;
        fx4 hi0 = lo0, hi1 = lo0, hi2 = lo0, hi3 = lo0;
        {
            h8_t af0 = *(const h8_t*)(hb + lr * 256 + ((0 * 64 + lq * 16) ^ ((lr & 7) << 4)));
            h8_t af1 = *(const h8_t*)(hb + lr * 256 + ((1 * 64 + lq * 16) ^ ((lr & 7) << 4)));
            h8_t af2 = *(const h8_t*)(hb + lr * 256 + ((2 * 64 + lq * 16) ^ ((lr & 7) << 4)));
            h8_t af3 = *(const h8_t*)(hb + lr * 256 + ((3 * 64 + lq * 16) ^ ((lr & 7) << 4)));
            lo0 = __builtin_amdgcn_mfma_f32_16x16x32_f16(af0, bf[0][0], lo0, 0, 0, 0);
            lo1 = __builtin_amdgcn_mfma_f32_16x16x32_f16(af0, bf[1][0], lo1, 0, 0, 0);
            lo2 = __builtin_amdgcn_mfma_f32_16x16x32_f16(af0, bf[2][0], lo2, 0, 0, 0);
            lo3 = __builtin_amdgcn_mfma_f32_16x16x32_f16(af0, bf[3][0], lo3, 0, 0, 0);
            hi0 = __builtin_amdgcn_mfma_f32_16x16x32_f16(af2, bf[0][2], hi0, 0, 0, 0);
            hi1 = __builtin_amdgcn_mfma_f32_16x16x32_f16(af2, bf[1][2], hi1, 0, 0, 0);
            hi2 = __builtin_amdgcn_mfma_f32_16x16x32_f16(af2, bf[2][2], hi2, 0, 0, 0);
            hi3 = __builtin_amdgcn_mfma_f32_16x16x32_f16(af2, bf[3][2], hi3, 0, 0, 0);
            lo0 = __builtin_amdgcn_mfma_f32_16x16x32_f16(af1, bf[0][1], lo0, 0, 0, 0);
            lo1 = __builtin_amdgcn_mfma_f32_16x16x32_f16(af1, bf[1][1], lo1, 0, 0, 0);
            lo2 = __builtin_amdgcn_mfma_f32_16x16x32_f16(af1, bf[2][1], lo2, 0, 0, 0);
            lo3 = __builtin_amdgcn_mfma_f32_16x16x32_f16(af1, bf[3][1], lo3, 0, 0, 0);
            hi0 = __builtin_amdgcn_mfma_f32_16x16x32_f16(af3, bf[0][3], hi0, 0, 0, 0);
            hi1 = __builtin_amdgcn_mfma_f32_16x16x32_f16(af3, bf[1][3], hi1, 0, 0, 0);
            hi2 = __builtin_amdgcn_mfma_f32_16x16x32_f16(af3, bf[2][3], hi2, 0, 0, 0);
            hi3 = __builtin_amdgcn_mfma_f32_16x16x32_f16(af3, bf[3][3], hi3, 0, 0, 0);
        }
        // phase 1: all 16 gate sums
        float sI[4], sF[4], sG[4], sO[4];
#pragma unroll
        for (int r = 0; r < 4; ++r) {
            sI[r] = (lo0[r] + hi0[r]) + (float)GA0[r];
            sF[r] = (lo1[r] + hi1[r]) + (float)GA1[r];
            sG[r] = (lo2[r] + hi2[r]) + (float)GA2[r];
            sO[r] = (lo3[r] + hi3[r]) + (float)GA3[r];
        }
        // phase 2: all 16 exps (independent -> trans unit pipelined)
        float eI[4], eF[4], eG[4], eO[4];
#pragma unroll
        for (int r = 0; r < 4; ++r) {
            eI[r] = fexp2(sI[r] * KS);
            eF[r] = fexp2(sF[r] * KS);
            eG[r] = fexp2(sG[r] * KT);
            eO[r] = fexp2(sO[r] * KS);
        }
        // phase 3: all 16 rcps
        float iv[4], fv[4], gq[4], ov[4];
#pragma unroll
        for (int r = 0; r < 4; ++r) {
            iv[r] = frcp(1.f + eI[r]);
            fv[r] = frcp(1.f + eF[r]);
            gq[r] = frcp(1.f + eG[r]);          // tanh = 1 - 2*gq
            ov[r] = frcp(1.f + eO[r]);
        }
        // phase 4: c update + tanh(c) (exp then rcp, batched)
        float eC[4];
#pragma unroll
        for (int r = 0; r < 4; ++r) {
            float gv = 1.f - 2.f * gq[r];
            c4[r] = fv[r] * c4[r] + iv[r] * gv;
            eC[r] = fexp2(c4[r] * KT);
        }
        char* hw = (char*)&hd[par ^ 1][0];
#pragma unroll
        for (int r = 0; r < 4; ++r) {
            float th = 1.f - 2.f * frcp(1.f + eC[r]);
            float h  = ov[r] * th;
            hl[r] = h;
            int m = lq * 4 + r;
            *(_Float16*)(hw + m * 256 + ((2 * u) ^ ((m & 7) << 4))) = (_Float16)(h * msk[r]);
        }
        xo0[(size_t)TT * NH] = hl[0];   // vmem: never drained by bar_lds
        xo1[(size_t)TT * NH] = hl[1];
        xo2[(size_t)TT * NH] = hl[2];
        xo3[(size_t)TT * NH] = hl[3];
        // reload this set for TT+4 (consumed 4 steps from now -> ~3.5 steps slack)
        int tn = min(TT + 4, NT - 1);
        GA0 = *(const h4_t*)(gp0 + (size_t)tn * TSTR);
        GA1 = *(const h4_t*)(gp1 + (size_t)tn * TSTR);
        GA2 = *(const h4_t*)(gp2 + (size_t)tn * TSTR);
        GA3 = *(const h4_t*)(gp3 + (size_t)tn * TSTR);
        bar_lds();   // hd writes visible; next step reads other parity
    };

    for (int t = 0; t < NT; t += 4) {
        STEPF(A0, A1, A2, A3, t + 0, 0);
        STEPF(B0, B1, B2, B3, t + 1, 1);
        STEPF(C0, C1, C2, C3, t + 2, 0);
        STEPF(D0, D1, D2, D3, t + 3, 1);
    }
#pragma unroll
    for (int r = 0; r < 4; ++r)
        hlast[(size_t)(b0 + lq * 4 + r) * NH + u] = hl[r];
}

extern "C" void kernel_launch(void* const* d_in, const int* in_sizes, int n_in,
                              void* d_out, int out_size, void* d_ws, size_t ws_size,
                              hipStream_t stream) {
    const float* x   = (const float*)d_in[0];
    const float* wih = (const float*)d_in[1];
    const float* whh = (const float*)d_in[2];
    const float* bih = (const float*)d_in[3];
    const float* bhh = (const float*)d_in[4];
    const float* pl  = (const float*)d_in[5];
    const float* plr = (const float*)d_in[6];
    const float* ux  = (const float*)d_in[7];
    const float* uh  = (const float*)d_in[8];

    float* out   = (float*)d_out;
    float* xout  = out;                                 // [B,T,H]
    float* hlast = out + (size_t)NB * NT * NH;          // [B,H]
    float* tail  = hlast + (size_t)NB * NH;             // reg, p, p_rec

    _Float16* G      = (_Float16*)d_ws;                 // slab layout, fits in NG*NMP
    _Float16* wih_h  = G + (size_t)NG * NMP;
    _Float16* whh_h  = wih_h + (size_t)NG * ND;
    _Float16* mask_x = whh_h + (size_t)NG * NH;         // [NB][ND] f16 (incl /(1-p))
    _Float16* mask_h = mask_x + (size_t)NB * ND;        // [NB][NH] f16 (incl /(1-pr))
    float*    partial = (float*)(mask_h + (size_t)NB * NH);   // 2 floats

    hipMemsetAsync(partial, 0, 2 * sizeof(float), stream);

    k_convert<<<64, 256, 0, stream>>>(wih, whh, pl, plr, ux, uh,
                                      wih_h, whh_h, mask_x, mask_h, partial);

    dim3 gg(NM / 128, NG / 128);
    k_gemm<<<gg, 256, 0, stream>>>(x, wih_h, bih, bhh, mask_x, G);

    k_tail<<<1, 512, 0, stream>>>(bih, bhh, pl, plr, partial, tail);

    k_lstm<<<NB / LBLK, 512, 0, stream>>>(G, whh_h, mask_h, xout, hlast);
}

// Round 12
// 549.086 us; speedup vs baseline: 1.0369x; 1.0369x over previous
//
#include <hip/hip_runtime.h>
#include <cstddef>

#define NB 256   // batch
#define NT 512   // time
#define ND 128   // input dim
#define NH 128   // hidden
#define NG 512   // 4*H
#define NM (NB * NT)     // input-GEMM rows (m = b*NT + t)
#define NMP (NM + 64)    // padded G stride (f16): breaks 2^18-byte L2 set aliasing

constexpr float F_EPS  = 1e-7f;
constexpr float F_TEMP = 0.1f;

typedef _Float16 h2_t __attribute__((ext_vector_type(2)));
typedef _Float16 h4_t __attribute__((ext_vector_type(4)));
typedef _Float16 h8_t __attribute__((ext_vector_type(8)));
typedef float    fx4  __attribute__((ext_vector_type(4)));

#if defined(__has_builtin)
#  if __has_builtin(__builtin_amdgcn_fdot2)
#    define FDOT2(a, b, c) __builtin_amdgcn_fdot2((a), (b), (c), false)
#  endif
#endif
#ifndef FDOT2
#  define FDOT2(a, b, c) ((c) + (float)(a)[0] * (float)(b)[0] + (float)(a)[1] * (float)(b)[1])
#endif

__device__ __forceinline__ float fexp2(float x) {
#if defined(__has_builtin)
#  if __has_builtin(__builtin_amdgcn_exp2f)
    return __builtin_amdgcn_exp2f(x);
#  else
    return exp2f(x);
#  endif
#else
    return exp2f(x);
#endif
}
__device__ __forceinline__ float frcp(float x) {
#if defined(__has_builtin)
#  if __has_builtin(__builtin_amdgcn_rcpf)
    return __builtin_amdgcn_rcpf(x);
#  else
    return 1.0f / x;
#  endif
#else
    return 1.0f / x;
#endif
}
__device__ __forceinline__ float fsig(float x) {
    return frcp(1.0f + fexp2(x * -1.44269504088896f));
}
__device__ __forceinline__ float ftanh(float x) {
    return 1.0f - 2.0f * frcp(1.0f + fexp2(x * 2.885390081777927f));
}
__device__ __forceinline__ float sig(float x) { return 1.0f / (1.0f + expf(-x)); }

// LDS-ordering-only barrier: does NOT drain vmcnt (global loads/stores stay in
// flight). lgkmcnt(0) orders our ds ops before the barrier; sched_barrier pins
// it (rule #18).
__device__ __forceinline__ void bar_lds() {
    asm volatile("s_waitcnt lgkmcnt(0)" ::: "memory");
    __builtin_amdgcn_sched_barrier(0);
    __builtin_amdgcn_s_barrier();
}

// ---------------- kernel 1: weight f16 conversion + w^2 sums + concrete masks -------
__global__ __launch_bounds__(256) void k_convert(const float* __restrict__ wih,
        const float* __restrict__ whh, const float* __restrict__ pl,
        const float* __restrict__ plr, const float* __restrict__ unif_x,
        const float* __restrict__ unif_h, _Float16* __restrict__ wih_h,
        _Float16* __restrict__ whh_h, _Float16* __restrict__ mask_x,
        _Float16* __restrict__ mask_h, float* __restrict__ partial) {
    int i = blockIdx.x * 256 + threadIdx.x;    // float4 index, 16384 total
    float4 a = ((const float4*)wih)[i];
    float4 b = ((const float4*)whh)[i];
    h4_t ah, bh;
    ah[0] = (_Float16)a.x; ah[1] = (_Float16)a.y; ah[2] = (_Float16)a.z; ah[3] = (_Float16)a.w;
    bh[0] = (_Float16)b.x; bh[1] = (_Float16)b.y; bh[2] = (_Float16)b.z; bh[3] = (_Float16)b.w;
    *(h4_t*)(wih_h + 4 * (size_t)i) = ah;
    *(h4_t*)(whh_h + 4 * (size_t)i) = bh;
    float sk = a.x * a.x + a.y * a.y + a.z * a.z + a.w * a.w;
    float sr = b.x * b.x + b.y * b.y + b.z * b.z + b.w * b.w;
    for (int off = 32; off; off >>= 1) {
        sk += __shfl_down(sk, off);
        sr += __shfl_down(sr, off);
    }
    if ((threadIdx.x & 63) == 0) {
        atomicAdd(partial + 0, sk);
        atomicAdd(partial + 1, sr);
    }
    // concrete-dropout masks: threads 0..8191 -> mask_x, 8192..16383 -> mask_h
    float p;
    const float* up;
    _Float16* mp;
    int mi;
    if (i < 8192) { p = sig(pl[0]);  up = unif_x; mp = mask_x; mi = i; }
    else          { p = sig(plr[0]); up = unif_h; mp = mask_h; mi = i - 8192; }
    float4 u = ((const float4*)up)[mi];
    float base = logf(p + F_EPS) - logf(1.f - p + F_EPS);
    float inv  = 1.f / (1.f - p);
    h4_t m4;
    {
        float uu[4] = {u.x, u.y, u.z, u.w};
#pragma unroll
        for (int e = 0; e < 4; ++e) {
            float lg = base + logf(uu[e] + F_EPS) - logf(1.f - uu[e] + F_EPS);
            float mk = 1.f - sig(lg / F_TEMP);
            m4[e] = (_Float16)(mk * inv);
        }
    }
    *(h4_t*)(mp + 4 * (size_t)mi) = m4;
}

// ---------------- kernel 1b: finalize scalar regularization outputs ----------------
__global__ void k_tail(const float* __restrict__ bih, const float* __restrict__ bhh,
                       const float* __restrict__ pl, const float* __restrict__ plr,
                       const float* __restrict__ partial, float* __restrict__ out_tail) {
    __shared__ float red[8];
    int t = threadIdx.x;  // 512 threads
    float v = bih[t], w2 = bhh[t];
    float sb = v * v + w2 * w2;
    for (int off = 32; off; off >>= 1) sb += __shfl_down(sb, off);
    int wid = t >> 6, lane = t & 63;
    if (lane == 0) red[wid] = sb;
    __syncthreads();
    if (t == 0) {
        float SB = 0.f;
        for (int i = 0; i < 8; i++) SB += red[i];
        float SK = partial[0], SR = partial[1];
        float p  = sig(pl[0]);
        float pr = sig(plr[0]);
        float wr = 1e-6f * (SK / (1.f - p) + SR / (1.f - pr));
        float br = 1e-6f * SB;
        float ek = p * logf(p) + (1.f - p) * logf(1.f - p);
        float er = pr * logf(pr) + (1.f - pr) * logf(1.f - pr);
        float dr = 1e-5f * ((float)ND * ek + (float)NH * er);
        out_tail[0] = wr + br + dr;
        out_tail[1] = p;
        out_tail[2] = pr;
    }
}

// ---------------- kernel 2: f16 MFMA input GEMM (r6-proven addressing) --------------
// G[j][m] with m = b*NT + t, stride NMP (padded). Mask from precomputed table.
__global__ __launch_bounds__(256, 2) void k_gemm(const float* __restrict__ x,
        const _Float16* __restrict__ wih_h, const float* __restrict__ bih,
        const float* __restrict__ bhh, const _Float16* __restrict__ mask_x,
        _Float16* __restrict__ Gp) {
    __shared__ _Float16 Alds[128 * 128];
    __shared__ _Float16 Wlds[128 * 128];
    __shared__ float bsum[128];
    int t  = threadIdx.x;
    int m0 = blockIdx.x * 128;           // row block (within one batch b: 128 | 512)
    int j0 = blockIdx.y * 128;           // gate-col block
    int b  = m0 >> 9;

    if (t < 128) bsum[t] = bih[j0 + t] + bhh[j0 + t];
    __syncthreads();

#pragma unroll
    for (int i = 0; i < 8; i++) {
        int s   = i * 256 + t;
        int row = s >> 4;                 // 0..127
        int s16 = s & 15;                 // 16B slot within row
        const float4* xp = (const float4*)(x + (size_t)(m0 + row) * ND + s16 * 8);
        float4 v0 = xp[0], v1 = xp[1];
        h8_t mk = *(const h8_t*)(mask_x + (size_t)b * ND + s16 * 8);
        h8_t hv;
        hv[0] = (_Float16)(v0.x * (float)mk[0]); hv[1] = (_Float16)(v0.y * (float)mk[1]);
        hv[2] = (_Float16)(v0.z * (float)mk[2]); hv[3] = (_Float16)(v0.w * (float)mk[3]);
        hv[4] = (_Float16)(v1.x * (float)mk[4]); hv[5] = (_Float16)(v1.y * (float)mk[5]);
        hv[6] = (_Float16)(v1.z * (float)mk[6]); hv[7] = (_Float16)(v1.w * (float)mk[7]);
        *(h8_t*)(&Alds[(size_t)row * 128 + ((s16 ^ (row & 7)) << 3)]) = hv;
        h8_t wv = *(const h8_t*)(wih_h + (size_t)(j0 + row) * ND + s16 * 8);
        *(h8_t*)(&Wlds[(size_t)row * 128 + ((s16 ^ (row & 7)) << 3)]) = wv;
    }
    __syncthreads();

    int w  = t >> 6, l = t & 63;
    int lr = l & 15, lg = l >> 4;
    fx4 acc[2][8] = {};
#pragma unroll
    for (int kk = 0; kk < 4; kk++) {
        h8_t af[2], bf[8];
#pragma unroll
        for (int mt = 0; mt < 2; mt++) {
            int r = 32 * w + 16 * mt + lr;
            af[mt] = *(const h8_t*)(&Alds[(size_t)r * 128 + (((4 * kk + lg) ^ (r & 7)) << 3)]);
        }
#pragma unroll
        for (int nt = 0; nt < 8; nt++) {
            int r = 16 * nt + lr;
            bf[nt] = *(const h8_t*)(&Wlds[(size_t)r * 128 + (((4 * kk + lg) ^ (r & 7)) << 3)]);
        }
#pragma unroll
        for (int mt = 0; mt < 2; mt++)
#pragma unroll
            for (int nt = 0; nt < 8; nt++)
                acc[mt][nt] = __builtin_amdgcn_mfma_f32_16x16x32_f16(af[mt], bf[nt], acc[mt][nt], 0, 0, 0);
    }

#pragma unroll
    for (int mt = 0; mt < 2; mt++)
#pragma unroll
        for (int nt = 0; nt < 8; nt++) {
            int j = j0 + 16 * nt + lr;
            int m = m0 + 32 * w + 16 * mt + 4 * lg;
            float bv = bsum[16 * nt + lr];
            h4_t o;
#pragma unroll
            for (int q = 0; q < 4; q++) o[q] = (_Float16)(acc[mt][nt][q] + bv);
            *(h4_t*)(Gp + (size_t)j * NMP + m) = o;
        }
}

// ---------------- kernel 3: recurrence — TWO batches per block (dual-r7) ------------
// 128 blocks x 512 threads. sub = tid>>8 selects batch b = 2*blockIdx.x + sub;
// waves 0-3 (sub 0) and 4-7 (sub 1) round-robin onto SIMDs 0-3 -> each SIMD
// hosts one wave of EACH independent recurrence: their serial chains (ds_read
// latency, dot chains, activations) hide each other (the TLP r7 lacked).
// Within a sub-block: r7's proven structure — thread owns column n (all 4
// gates) for k-half `half`: w[4][32] h2 = 128 VGPR (pinned, waves_per_eu(2,2)
// caps alloc at 256 so no demotion). Per step: 8 broadcast ds_read_b128,
// 128 fdot2, 4x shfl_xor(32) half-combine (symmetric -> identical sums both
// halves), 4 fast activations, ONE LDS-only barrier. hd[sub][2][128] dbuf.
__global__ __launch_bounds__(512) __attribute__((amdgpu_waves_per_eu(2, 2)))
void k_lstm(const _Float16* __restrict__ Gp, const _Float16* __restrict__ whh_h,
            const _Float16* __restrict__ maskh,
            float* __restrict__ xout, float* __restrict__ hlast) {
    __shared__ _Float16 hd[2][2][128];   // [sub][parity][unit]
    int tid  = threadIdx.x;              // 0..511
    int sub  = tid >> 8;                 // batch-of-pair
    int l    = tid & 63;
    int wv   = (tid >> 6) & 3;           // wave within sub-block
    int n    = wv * 32 + (l & 31);       // hidden column owned
    int half = l >> 5;                   // k-half
    int b    = blockIdx.x * 2 + sub;

    h2_t w[4][32];
#pragma unroll
    for (int gq = 0; gq < 4; gq++) {
        const _Float16* wr = whh_h + (size_t)(gq * 128 + n) * NH + 64 * half;
#pragma unroll
        for (int i = 0; i < 8; i++) {
            h8_t a = *(const h8_t*)(wr + 8 * i);
#pragma unroll
            for (int q = 0; q < 4; q++)
                w[gq][4 * i + q] = (h2_t){a[2 * q], a[2 * q + 1]};
        }
    }

    float msk = (float)maskh[(size_t)b * NH + n];
    float h = 0.f, c = 0.f;
    if (half == 0) hd[sub][0][n] = (_Float16)0.f;

    // 4 G streams (gate rows n, n+128, n+256, n+384); both halves read the
    // same addresses -> hardware-merged. h8 per 8 steps, prefetched 1 window.
    const _Float16* gp0 = Gp + (size_t)(0 * 128 + n) * NMP + (size_t)b * NT;
    const _Float16* gp1 = Gp + (size_t)(1 * 128 + n) * NMP + (size_t)b * NT;
    const _Float16* gp2 = Gp + (size_t)(2 * 128 + n) * NMP + (size_t)b * NT;
    const _Float16* gp3 = Gp + (size_t)(3 * 128 + n) * NMP + (size_t)b * NT;
    float* xo = xout + (size_t)b * NT * NH + n;   // stored by half==0 lanes

    h8_t g0 = *(const h8_t*)(gp0);
    h8_t g1 = *(const h8_t*)(gp1);
    h8_t g2 = *(const h8_t*)(gp2);
    h8_t g3 = *(const h8_t*)(gp3);
    __syncthreads();          // hd[*][0] init visible

    for (int w8 = 0; w8 < NT / 8; w8++) {
        // pin W_hh in VGPRs (loop-carried asm outputs can't be rematerialized)
#pragma unroll
        for (int gq = 0; gq < 4; gq++)
#pragma unroll
            for (int i = 0; i < 32; i++) asm volatile("" : "+v"(w[gq][i]));
        h8_t n0 = g0, n1 = g1, n2 = g2, n3 = g3;
        if (w8 + 1 < NT / 8) {
            n0 = *(const h8_t*)(gp0 + 8 * (w8 + 1));   // in flight ~8 steps
            n1 = *(const h8_t*)(gp1 + 8 * (w8 + 1));
            n2 = *(const h8_t*)(gp2 + 8 * (w8 + 1));
            n3 = *(const h8_t*)(gp3 + 8 * (w8 + 1));
        }
#pragma unroll
        for (int e = 0; e < 8; e++) {
            const _Float16* hb = &hd[sub][e & 1][64 * half];   // this thread's 128B k-half
            float a0a = 0.f, a0b = 0.f, a1a = 0.f, a1b = 0.f;
            float a2a = 0.f, a2b = 0.f, a3a = 0.f, a3b = 0.f;
#pragma unroll
            for (int i = 0; i < 8; i++) {
                h8_t hv = *(const h8_t*)(hb + 8 * i);     // broadcast read
                h2_t x0 = (h2_t){hv[0], hv[1]}, x1 = (h2_t){hv[2], hv[3]};
                h2_t x2 = (h2_t){hv[4], hv[5]}, x3 = (h2_t){hv[6], hv[7]};
                a0a = FDOT2(x0, w[0][4 * i + 0], a0a);
                a0b = FDOT2(x1, w[0][4 * i + 1], a0b);
                a0a = FDOT2(x2, w[0][4 * i + 2], a0a);
                a0b = FDOT2(x3, w[0][4 * i + 3], a0b);
                a1a = FDOT2(x0, w[1][4 * i + 0], a1a);
                a1b = FDOT2(x1, w[1][4 * i + 1], a1b);
                a1a = FDOT2(x2, w[1][4 * i + 2], a1a);
                a1b = FDOT2(x3, w[1][4 * i + 3], a1b);
                a2a = FDOT2(x0, w[2][4 * i + 0], a2a);
                a2b = FDOT2(x1, w[2][4 * i + 1], a2b);
                a2a = FDOT2(x2, w[2][4 * i + 2], a2a);
                a2b = FDOT2(x3, w[2][4 * i + 3], a2b);
                a3a = FDOT2(x0, w[3][4 * i + 0], a3a);
                a3b = FDOT2(x1, w[3][4 * i + 1], a3b);
                a3a = FDOT2(x2, w[3][4 * i + 2], a3a);
                a3b = FDOT2(x3, w[3][4 * i + 3], a3b);
            }
            float s0 = a0a + a0b, s1 = a1a + a1b;
            float s2 = a2a + a2b, s3 = a3a + a3b;
            // combine k-halves (symmetric: both halves end with full sums)
            s0 += __shfl_xor(s0, 32, 64);
            s1 += __shfl_xor(s1, 32, 64);
            s2 += __shfl_xor(s2, 32, 64);
            s3 += __shfl_xor(s3, 32, 64);
            s0 += (float)g0[e];
            s1 += (float)g1[e];
            s2 += (float)g2[e];
            s3 += (float)g3[e];
            float iv = fsig(s0), fv = fsig(s1);
            float gv = ftanh(s2), ov = fsig(s3);
            c = fv * c + iv * gv;
            h = ov * ftanh(c);
            if (half == 0) {
                hd[sub][(e & 1) ^ 1][n] = (_Float16)(h * msk);
                xo[(size_t)(8 * w8 + e) * NH] = h;   // never drained by bar_lds
            }
            bar_lds();         // hd writes visible; next step reads other parity
        }
        g0 = n0; g1 = n1; g2 = n2; g3 = n3;
    }
    if (half == 0) hlast[(size_t)b * NH + n] = h;
}

extern "C" void kernel_launch(void* const* d_in, const int* in_sizes, int n_in,
                              void* d_out, int out_size, void* d_ws, size_t ws_size,
                              hipStream_t stream) {
    const float* x   = (const float*)d_in[0];
    const float* wih = (const float*)d_in[1];
    const float* whh = (const float*)d_in[2];
    const float* bih = (const float*)d_in[3];
    const float* bhh = (const float*)d_in[4];
    const float* pl  = (const float*)d_in[5];
    const float* plr = (const float*)d_in[6];
    const float* ux  = (const float*)d_in[7];
    const float* uh  = (const float*)d_in[8];

    float* out   = (float*)d_out;
    float* xout  = out;                                 // [B,T,H]
    float* hlast = out + (size_t)NB * NT * NH;          // [B,H]
    float* tail  = hlast + (size_t)NB * NH;             // reg, p, p_rec

    _Float16* G      = (_Float16*)d_ws;                 // [NG][NMP] f16
    _Float16* wih_h  = G + (size_t)NG * NMP;
    _Float16* whh_h  = wih_h + (size_t)NG * ND;
    _Float16* mask_x = whh_h + (size_t)NG * NH;         // [NB][ND] f16 (incl /(1-p))
    _Float16* mask_h = mask_x + (size_t)NB * ND;        // [NB][NH] f16 (incl /(1-pr))
    float*    partial = (float*)(mask_h + (size_t)NB * NH);   // 2 floats

    hipMemsetAsync(partial, 0, 2 * sizeof(float), stream);

    k_convert<<<64, 256, 0, stream>>>(wih, whh, pl, plr, ux, uh,
                                      wih_h, whh_h, mask_x, mask_h, partial);

    dim3 gg(NM / 128, NG / 128);
    k_gemm<<<gg, 256, 0, stream>>>(x, wih_h, bih, bhh, mask_x, G);

    k_tail<<<1, 512, 0, stream>>>(bih, bhh, pl, plr, partial, tail);

    k_lstm<<<NB / 2, 512, 0, stream>>>(G, whh_h, mask_h, xout, hlast);
}